// Round 5
// baseline (490.275 us; speedup 1.0000x reference)
//
#include <hip/hip_runtime.h>

#define HW     4096
#define CKD    64
#define CVD    512
#define NBATCH 8
#define BQ     128
#define BM     128
#define NIT    32      // HW / BM
#define PSH    128     // P row = 128 shorts, 16 chunks of 8 shorts, XOR-swizzled
#define TST    72      // prep transpose tile stride (shorts); 144 B, 16B-aligned

typedef __attribute__((ext_vector_type(8))) short  short8;
typedef __attribute__((ext_vector_type(4))) float  floatx4;
typedef __attribute__((ext_vector_type(4))) int    intx4;
typedef __attribute__((ext_vector_type(2))) int    intx2;

#if __has_builtin(__builtin_amdgcn_exp2f)
#define EXP2F(x) __builtin_amdgcn_exp2f(x)
#else
#define EXP2F(x) exp2f(x)
#endif

static __device__ __forceinline__ unsigned short f2bf(float f) {
  unsigned u = __float_as_uint(f);
  u = (u + 0x7fffu + ((u >> 16) & 1u)) >> 16;   // RTNE
  return (unsigned short)u;
}
static __device__ __forceinline__ unsigned pack_rtne(float a, float b) {
  return (unsigned)f2bf(a) | ((unsigned)f2bf(b) << 16);
}
// round-half-up pack: 3 ops
static __device__ __forceinline__ unsigned pack_fast(float a, float b) {
  unsigned ua = __float_as_uint(a) + 0x8000u;
  unsigned ub = __float_as_uint(b) + 0x8000u;
  return (ua >> 16) | (ub & 0xffff0000u);
}
static __device__ __forceinline__ short8 ld_bf16x8(const unsigned short* p) {
  union { intx4 i; short8 s; } u;
  u.i = *(const intx4*)p;
  return u.s;
}
static __device__ __forceinline__ short8 cvt_f32x8(const float* p) {
  short8 f;
  #pragma unroll
  for (int j = 0; j < 8; ++j) f[j] = (short)f2bf(p[j]);
  return f;
}
static __device__ __forceinline__ short8 cvt_f32x8_strided(const float* p) {
  short8 f;
  #pragma unroll
  for (int j = 0; j < 8; ++j) f[j] = (short)f2bf(p[(size_t)j * HW]);
  return f;
}

// ---- prep: Mk/Qk f32 [b][c][m] -> bf16 [b][m][c] (transpose); Mv f32 -> bf16
__global__ __launch_bounds__(256) void prep(
    const float* __restrict__ Mk, const float* __restrict__ Qk,
    const float* __restrict__ Mv,
    unsigned short* __restrict__ mkT, unsigned short* __restrict__ qkT,
    unsigned short* __restrict__ mvB)
{
  const int bid = blockIdx.x, t = threadIdx.x;
  if (bid < 256) {
    // transpose one 64c x 256m tile; wave reads one full 1KB row per pass
    __shared__ alignas(16) short tile[256 * TST];   // 36864 B
    const int tens = bid >> 7;                       // 0: Mk, 1: Qk
    const int r    = bid & 127;
    const int b    = r >> 4;
    const int m0   = (r & 15) * 256;
    const float* src = (tens ? Qk : Mk) + (size_t)b * CKD * HW;
    unsigned short* dst = (tens ? qkT : mkT) + (size_t)b * HW * CKD;

    const int cw   = t >> 6;          // wave id 0..3 -> row within pass
    const int posf = (t & 63) * 4;
    #pragma unroll
    for (int pass = 0; pass < 16; ++pass) {
      const int c = pass * 4 + cw;
      float4 v = *(const float4*)(src + (size_t)c * HW + m0 + posf);
      tile[(posf + 0) * TST + c] = (short)f2bf(v.x);
      tile[(posf + 1) * TST + c] = (short)f2bf(v.y);
      tile[(posf + 2) * TST + c] = (short)f2bf(v.z);
      tile[(posf + 3) * TST + c] = (short)f2bf(v.w);
    }
    __syncthreads();
    // thread t writes dst row m0+t (64 shorts = 128 B contiguous)
    unsigned short* drow = dst + (size_t)(m0 + t) * CKD;
    #pragma unroll
    for (int k = 0; k < 8; ++k) {
      intx4 x = *(const intx4*)(tile + t * TST + k * 8);
      *(intx4*)(drow + k * 8) = x;
    }
  } else {
    // mv convert: fully coalesced, 8 passes of (float4 -> 2 packed dwords)
    const size_t base = (size_t)(bid - 256) * 8192;
    #pragma unroll
    for (int p = 0; p < 8; ++p) {
      const size_t idx = base + p * 1024 + t * 4;
      float4 v = *(const float4*)(Mv + idx);
      intx2 r2;
      r2[0] = (int)pack_rtne(v.x, v.y);
      r2[1] = (int)pack_rtne(v.z, v.w);
      *(intx2*)(mvB + idx) = r2;
    }
  }
}

template<bool BF>
__global__ __launch_bounds__(512, 4) void attn_main(
    const void* __restrict__ MkP, const void* __restrict__ QkP,
    const void* __restrict__ MvP, float* __restrict__ Out)
{
  __shared__ alignas(16) short Pt[2][BQ * PSH];   // 65536 B
  __shared__ float lsum[BQ];

  const int bx   = blockIdx.x;
  const int b    = bx & 7;             // batch -> XCD affinity
  const int q0   = ((bx >> 3) & 31) * BQ;
  const int h    = bx >> 8;            // cv half: 0 or 1
  const int tid  = threadIdx.x;
  const int w    = tid >> 6;
  const int lane = tid & 63;
  const int quad = lane >> 4;
  const int col  = lane & 15;

  const size_t esz = BF ? 2 : 4;
  const char* mkB = (const char*)MkP + (size_t)b * CKD * HW * esz;  // BF: [m][c]
  const char* mvB = (const char*)MvP + (size_t)b * CVD * HW * esz;  // [cv][m]
  float* out = Out + (size_t)b * CVD * HW;

  if (tid < BQ) lsum[tid] = 0.0f;

  // qk B-fragments (fixed per block): wave w owns q-tile w
  short8 bq0, bq1;
  {
    const int q = q0 + w * 16 + col;
    if constexpr (BF) {
      const unsigned short* qkT = (const unsigned short*)QkP + (size_t)b * HW * CKD;
      bq0 = ld_bf16x8(qkT + (size_t)q * CKD + quad * 8);
      bq1 = ld_bf16x8(qkT + (size_t)q * CKD + 32 + quad * 8);
    } else {
      const float* qk = (const float*)QkP + (size_t)b * CKD * HW;
      bq0 = cvt_f32x8_strided(qk + (size_t)(quad * 8) * HW + q);
      bq1 = cvt_f32x8_strided(qk + (size_t)(32 + quad * 8) * HW + q);
    }
  }

  floatx4 acc[2][8];   // wave owns cv rows [h*256 + w*32, +32), all 128 q
  #pragma unroll
  for (int i = 0; i < 2; ++i)
    #pragma unroll
    for (int j = 0; j < 8; ++j) acc[i][j] = (floatx4)0.0f;
  float lacc = 0.0f;
  const float SC = 0.18033688011112042f;   // (1/8) * log2(e)
  const int cvb = h * 256 + w * 32;
  // P write position pieces (swizzled chunk layout)
  const int prow = (w * 16 + col) * PSH;
  const int wsub = (quad & 1) * 4;

  // ---- GEMM1 for one 128m stripe: wave w does q-tile w, m-tiles 0..7 ----
  auto gemm1 = [&](short* Pb, int m0) {
    #pragma unroll
    for (int mh = 0; mh < 8; ++mh) {
      const int m = m0 + mh * 16 + col;
      short8 a0, a1;
      if constexpr (BF) {
        const unsigned short* p = (const unsigned short*)mkB + (size_t)m * CKD + quad * 8;
        a0 = ld_bf16x8(p);
        a1 = ld_bf16x8(p + 32);
      } else {
        const float* mk = (const float*)mkB;
        a0 = cvt_f32x8_strided(mk + (size_t)(quad * 8) * HW + m);
        a1 = cvt_f32x8_strided(mk + (size_t)(32 + quad * 8) * HW + m);
      }
      floatx4 s = (floatx4)0.0f;
      s = __builtin_amdgcn_mfma_f32_16x16x32_bf16(a0, bq0, s, 0, 0, 0);
      s = __builtin_amdgcn_mfma_f32_16x16x32_bf16(a1, bq1, s, 0, 0, 0);
      const float p0 = EXP2F(s[0] * SC);
      const float p1 = EXP2F(s[1] * SC);
      const float p2 = EXP2F(s[2] * SC);
      const float p3 = EXP2F(s[3] * SC);
      lacc += (p0 + p1) + (p2 + p3);
      intx2 pv;
      pv[0] = (int)pack_fast(p0, p1);
      pv[1] = (int)pack_fast(p2, p3);
      const int phys = (mh * 2 + (quad >> 1)) ^ col;   // 16B-chunk swizzle
      *(intx2*)(Pb + prow + phys * 8 + wsub) = pv;
    }
  };

  gemm1(&Pt[0][0], 0);

  for (int it = 0; it < NIT; ++it) {
    __syncthreads();                 // P(it) ready; other buffer free
    const short* Pb = &Pt[it & 1][0];
    const int m0 = it * BM;

    // ---- GEMM2: O[cv][q] += mv[cv][m] * P[m][q]
    short8 av[2][2];
    #pragma unroll
    for (int ch = 0; ch < 2; ++ch) {
      if constexpr (BF)
        av[0][ch] = ld_bf16x8((const unsigned short*)mvB +
                              (size_t)(cvb + ch * 16 + col) * HW + m0 + quad * 8);
      else
        av[0][ch] = cvt_f32x8((const float*)mvB +
                              (size_t)(cvb + ch * 16 + col) * HW + m0 + quad * 8);
    }
    #pragma unroll
    for (int ks = 0; ks < 4; ++ks) {
      if (ks < 3) {
        #pragma unroll
        for (int ch = 0; ch < 2; ++ch) {
          if constexpr (BF)
            av[(ks + 1) & 1][ch] = ld_bf16x8((const unsigned short*)mvB +
                (size_t)(cvb + ch * 16 + col) * HW + m0 + (ks + 1) * 32 + quad * 8);
          else
            av[(ks + 1) & 1][ch] = cvt_f32x8((const float*)mvB +
                (size_t)(cvb + ch * 16 + col) * HW + m0 + (ks + 1) * 32 + quad * 8);
        }
      }
      #pragma unroll
      for (int qh = 0; qh < 8; ++qh) {
        const int phys = (ks * 4 + quad) ^ col;      // 16B-chunk swizzle
        union { intx4 i; short8 s; } u;
        u.i = *(const intx4*)(Pb + (qh * 16 + col) * PSH + phys * 8);
        acc[0][qh] = __builtin_amdgcn_mfma_f32_16x16x32_bf16(av[ks & 1][0], u.s, acc[0][qh], 0, 0, 0);
        acc[1][qh] = __builtin_amdgcn_mfma_f32_16x16x32_bf16(av[ks & 1][1], u.s, acc[1][qh], 0, 0, 0);
      }
    }

    if (it + 1 < NIT)
      gemm1(&Pt[(it + 1) & 1][0], m0 + BM);
  }

  atomicAdd(&lsum[w * 16 + col], lacc);
  __syncthreads();

  float rl[8];
  #pragma unroll
  for (int qh = 0; qh < 8; ++qh) rl[qh] = 1.0f / lsum[qh * 16 + col];

  #pragma unroll
  for (int ch = 0; ch < 2; ++ch) {
    #pragma unroll
    for (int r = 0; r < 4; ++r) {
      const int cv = cvb + ch * 16 + quad * 4 + r;
      float* orow = out + (size_t)cv * HW + q0 + col;
      #pragma unroll
      for (int qh = 0; qh < 8; ++qh)
        __builtin_nontemporal_store(acc[ch][qh][r] * rl[qh], orow + qh * 16);
    }
  }
}

extern "C" void kernel_launch(void* const* d_in, const int* in_sizes, int n_in,
                              void* d_out, int out_size, void* d_ws, size_t ws_size,
                              hipStream_t stream) {
  const float* Mk = (const float*)d_in[0];
  const float* Qk = (const float*)d_in[1];
  const float* Mv = (const float*)d_in[2];
  float* Out = (float*)d_out;
  (void)in_sizes; (void)n_in; (void)out_size;

  const size_t NMK = (size_t)NBATCH * CKD * HW;   // 2,097,152
  const size_t NMV = (size_t)NBATCH * CVD * HW;   // 16,777,216
  const size_t need = (2 * NMK + NMV) * 2;        // 41,943,040 B

  if (ws_size >= need) {
    unsigned short* mkT = (unsigned short*)d_ws;
    unsigned short* qkT = mkT + NMK;
    unsigned short* mvW = qkT + NMK;
    const int prep_blocks = 256 + (int)(NMV / 8192);   // 256 + 2048
    prep<<<prep_blocks, 256, 0, stream>>>(Mk, Qk, Mv, mkT, qkT, mvW);
    attn_main<true><<<2 * NBATCH * (HW / BQ), 512, 0, stream>>>(mkT, qkT, mvW, Out);
  } else {
    attn_main<false><<<2 * NBATCH * (HW / BQ), 512, 0, stream>>>(Mk, Qk, Mv, Out);
  }
}